// Round 6
// baseline (164.301 us; speedup 1.0000x reference)
//
#include <hip/hip_runtime.h>
#include <hip/hip_bf16.h>
#include <cstdint>

#define BATCH 4096
#define DIN   512
#define DH    256
#define DG    128
#define NH    8
#define NTOT  3328
#define S1    264    // padded f32 row stride for z1 LDS

typedef __bf16 bf16x8 __attribute__((ext_vector_type(8)));
typedef float  f32x4  __attribute__((ext_vector_type(4)));

__device__ __forceinline__ unsigned short f2bf(float f) {
    union { float f; uint32_t u; } v; v.f = f;
    uint32_t u = v.u;
    u += 0x7fffu + ((u >> 16) & 1u);
    return (unsigned short)(u >> 16);
}
__device__ __forceinline__ float bf2f(unsigned short s) {
    union { uint32_t u; float f; } v; v.u = ((uint32_t)s) << 16;
    return v.f;
}
__device__ __forceinline__ void bf8_to_f8(uint4 u, float4& a, float4& b) {
    a.x = bf2f((unsigned short)(u.x & 0xffff)); a.y = bf2f((unsigned short)(u.x >> 16));
    a.z = bf2f((unsigned short)(u.y & 0xffff)); a.w = bf2f((unsigned short)(u.y >> 16));
    b.x = bf2f((unsigned short)(u.z & 0xffff)); b.y = bf2f((unsigned short)(u.z >> 16));
    b.z = bf2f((unsigned short)(u.w & 0xffff)); b.w = bf2f((unsigned short)(u.w >> 16));
}

__device__ __forceinline__ void async16(const unsigned short* g, unsigned short* l) {
    __builtin_amdgcn_global_load_lds(
        (const __attribute__((address_space(1))) unsigned int*)(uintptr_t)g,
        (__attribute__((address_space(3))) unsigned int*)(uintptr_t)l,
        16, 0, 0);
}

// ---------------- merged prep: cvt_x + transpose/concat weights (R5-proven) ----------------
__global__ __launch_bounds__(256) void prep_kernel(const float* __restrict__ x,
                                                   const float* __restrict__ Wh,
                                                   const float* __restrict__ Wz1,
                                                   const float* __restrict__ Wz2,
                                                   unsigned short* __restrict__ xb,
                                                   unsigned short* __restrict__ Wt) {
    __shared__ float tile[32][33];
    int bid = blockIdx.x;
    int t = threadIdx.x;
    if (bid < 2048) {
        int i = (bid * 256 + t) * 4;
        float4 v = *(const float4*)(x + i);
        ushort4 o;
        o.x = f2bf(v.x); o.y = f2bf(v.y); o.z = f2bf(v.z); o.w = f2bf(v.w);
        *(ushort4*)(xb + i) = o;
        return;
    }
    int b2 = bid - 2048;
    int n0 = (b2 % 104) * 32;
    int k0 = (b2 / 104) * 32;
    const float* W; int ldn, nl;
    if (n0 < 256)       { W = Wh;  ldn = 256;  nl = n0; }
    else if (n0 < 2304) { W = Wz1; ldn = 2048; nl = n0 - 256; }
    else                { W = Wz2; ldn = 1024; nl = n0 - 2304; }
    int tx = t & 31, ty = t >> 5;
    #pragma unroll
    for (int i = 0; i < 4; i++) {
        int kk = ty + i * 8;
        tile[kk][tx] = W[(size_t)(k0 + kk) * ldn + nl + tx];
    }
    __syncthreads();
    #pragma unroll
    for (int i = 0; i < 4; i++) {
        int nn = ty + i * 8;
        Wt[(size_t)(n0 + nn) * 512 + k0 + tx] = f2bf(tile[tx][nn]);
    }
}

// ------------- fused GEMM: Zb[4096][3328](bf16) = xb @ Wt^T (R5-proven) -------------
__global__ __launch_bounds__(256) void gemm_kernel(const unsigned short* __restrict__ xb,
                                                   const unsigned short* __restrict__ Wt,
                                                   unsigned short* __restrict__ Zb) {
    __shared__ unsigned short As[128 * 64];
    __shared__ unsigned short Bs[128 * 64];
    const int m0 = blockIdx.y * 128;
    const int n0 = blockIdx.x * 128;
    const int t = threadIdx.x;
    const int w = t >> 6, lane = t & 63;
    const int wm = (w >> 1) * 64, wn = (w & 1) * 64;
    const int lrow = lane & 15, q = lane >> 4;

    f32x4 acc[4][4] = {};

    for (int k0 = 0; k0 < DIN; k0 += 64) {
        __syncthreads();
        #pragma unroll
        for (int j = 0; j < 4; j++) {
            int gidx = (w * 4 + j) * 64 + lane;
            int row = gidx >> 3, slot = gidx & 7;
            int src = slot ^ (row & 7);
            const unsigned short* ga = xb + (size_t)(m0 + row) * DIN + k0 + src * 8;
            const unsigned short* gb = Wt + (size_t)(n0 + row) * DIN + k0 + src * 8;
            async16(ga, As + (w * 4 + j) * 512);
            async16(gb, Bs + (w * 4 + j) * 512);
        }
        __syncthreads();
        #pragma unroll
        for (int ks = 0; ks < 2; ks++) {
            bf16x8 af[4], bfr[4];
            #pragma unroll
            for (int i = 0; i < 4; i++) {
                int row = wm + i * 16 + lrow;
                int phys = (ks * 4 + q) ^ (row & 7);
                af[i] = *reinterpret_cast<const bf16x8*>(As + row * 64 + phys * 8);
            }
            #pragma unroll
            for (int j = 0; j < 4; j++) {
                int row = wn + j * 16 + lrow;
                int phys = (ks * 4 + q) ^ (row & 7);
                bfr[j] = *reinterpret_cast<const bf16x8*>(Bs + row * 64 + phys * 8);
            }
            #pragma unroll
            for (int i = 0; i < 4; i++)
                #pragma unroll
                for (int j = 0; j < 4; j++)
                    acc[i][j] = __builtin_amdgcn_mfma_f32_16x16x32_bf16(af[i], bfr[j], acc[i][j], 0, 0, 0);
        }
    }
    #pragma unroll
    for (int i = 0; i < 4; i++)
        #pragma unroll
        for (int j = 0; j < 4; j++) {
            int col = n0 + wn + j * 16 + lrow;
            int rbase = m0 + wm + i * 16 + q * 4;
            #pragma unroll
            for (int r = 0; r < 4; r++)
                Zb[(size_t)(rbase + r) * NTOT + col] = f2bf(acc[i][j][r]);
        }
}

// ------- per-batch-PAIR: LN -> h ; Gram ; MFMA tanh ; y (R5 body, dual-row) -------
__global__ __launch_bounds__(256) void attn_kernel(const unsigned short* __restrict__ Zb,
                                                   const float* __restrict__ bh,
                                                   const float* __restrict__ lns,
                                                   const float* __restrict__ lnb,
                                                   float* __restrict__ h_out,
                                                   float* __restrict__ y_out) {
    __shared__ float z1s[2][9 * S1];           // rows 0..7 = z1 heads (f32), row 8 = ones
    __shared__ float z2s[2][NH * DG];
    __shared__ float hs[2][DH];
    __shared__ float GL[2][9][9];
    __shared__ unsigned short z1cb[2][DH * 8]; // centered z1, bf16, [d][h]
    __shared__ unsigned short z2A[2][DG * 8];  // z2 * A, bf16, [g][h]
    __shared__ unsigned short zpad[8];
    __shared__ float red[2][4][3];
    const int b0 = blockIdx.x * 2;
    const int t = threadIdx.x;
    const int wv = t >> 6, lane = t & 63;
    const unsigned short* Zr0 = Zb + (size_t)b0 * NTOT;
    const unsigned short* Zr1 = Zb + (size_t)(b0 + 1) * NTOT;

    // ---- stage both rows: bf16 -> f32 LDS ----
    {
        int hh = t >> 5, d0 = (t & 31) * 8;
        uint4 u0 = *(const uint4*)(Zr0 + 256 + t * 8);
        uint4 u1 = *(const uint4*)(Zr1 + 256 + t * 8);
        float4 a, c;
        bf8_to_f8(u0, a, c);
        *(float4*)(&z1s[0][hh * S1 + d0])     = a;
        *(float4*)(&z1s[0][hh * S1 + d0 + 4]) = c;
        bf8_to_f8(u1, a, c);
        *(float4*)(&z1s[1][hh * S1 + d0])     = a;
        *(float4*)(&z1s[1][hh * S1 + d0 + 4]) = c;
        if (t < 128) {
            uint4 w0 = *(const uint4*)(Zr0 + 2304 + t * 8);
            uint4 w1 = *(const uint4*)(Zr1 + 2304 + t * 8);
            float4 e, f;
            bf8_to_f8(w0, e, f);
            *(float4*)(&z2s[0][t * 8])     = e;
            *(float4*)(&z2s[0][t * 8 + 4]) = f;
            bf8_to_f8(w1, e, f);
            *(float4*)(&z2s[1][t * 8])     = e;
            *(float4*)(&z2s[1][t * 8 + 4]) = f;
        }
        z1s[0][8 * S1 + t] = 1.0f;
        z1s[1][8 * S1 + t] = 1.0f;
        if (t < 8) zpad[t] = 0;
    }
    // ---- LN partials, both rows (hpre direct from global) ----
    const float bhv = bh[t];
    float v0 = fmaxf(bf2f(Zr0[t]) + bhv, 0.0f);
    float v1 = fmaxf(bf2f(Zr1[t]) + bhv, 0.0f);
    float s0 = v0, q0 = v0 * v0, s1 = v1, q1 = v1 * v1;
    #pragma unroll
    for (int m = 32; m >= 1; m >>= 1) {
        s0 += __shfl_xor(s0, m, 64); q0 += __shfl_xor(q0, m, 64);
        s1 += __shfl_xor(s1, m, 64); q1 += __shfl_xor(q1, m, 64);
    }
    if (lane == 0) {
        red[0][wv][0] = s0; red[0][wv][1] = q0;
        red[1][wv][0] = s1; red[1][wv][1] = q1;
    }
    __syncthreads();   // (#1) staging + LN partials

    // ---- LN final, both rows ----
    const float lnsv = lns[t], lnbv = lnb[t];
    {
        float ss = red[0][0][0] + red[0][1][0] + red[0][2][0] + red[0][3][0];
        float qq = red[0][0][1] + red[0][1][1] + red[0][2][1] + red[0][3][1];
        float mu = ss * (1.0f / 256.0f);
        float var = qq * (1.0f / 256.0f) - mu * mu;
        float hval = (v0 - mu) * rsqrtf(var + 1e-6f) * lnsv + lnbv;
        hs[0][t] = hval;
        h_out[(size_t)b0 * DH + t] = hval;
        float hp = hval;
        #pragma unroll
        for (int m = 32; m >= 1; m >>= 1) hp += __shfl_xor(hp, m, 64);
        if (lane == 0) red[0][wv][2] = hp;
    }
    {
        float ss = red[1][0][0] + red[1][1][0] + red[1][2][0] + red[1][3][0];
        float qq = red[1][0][1] + red[1][1][1] + red[1][2][1] + red[1][3][1];
        float mu = ss * (1.0f / 256.0f);
        float var = qq * (1.0f / 256.0f) - mu * mu;
        float hval = (v1 - mu) * rsqrtf(var + 1e-6f) * lnsv + lnbv;
        hs[1][t] = hval;
        h_out[(size_t)(b0 + 1) * DH + t] = hval;
        float hp = hval;
        #pragma unroll
        for (int m = 32; m >= 1; m >>= 1) hp += __shfl_xor(hp, m, 64);
        if (lane == 0) red[1][wv][2] = hp;
    }

    // ---- Gram, both rows per task: 11 tasks/wave ----
    #pragma unroll
    for (int j = 0; j < 11; j++) {
        int task = wv * 11 + j;
        int h = 0, rem = task;
        while (rem >= 9 - h) { rem -= 9 - h; h++; }   // wave-uniform
        int h2 = h + rem;
        float4 a0 = *(const float4*)(&z1s[0][h  * S1 + lane * 4]);
        float4 c0 = *(const float4*)(&z1s[0][h2 * S1 + lane * 4]);
        float4 a1 = *(const float4*)(&z1s[1][h  * S1 + lane * 4]);
        float4 c1 = *(const float4*)(&z1s[1][h2 * S1 + lane * 4]);
        float p0 = a0.x * c0.x + a0.y * c0.y + a0.z * c0.z + a0.w * c0.w;
        float p1 = a1.x * c1.x + a1.y * c1.y + a1.z * c1.z + a1.w * c1.w;
        #pragma unroll
        for (int m = 32; m >= 1; m >>= 1) {
            p0 += __shfl_xor(p0, m, 64);
            p1 += __shfl_xor(p1, m, 64);
        }
        if (lane == 0) {
            GL[0][h][h2] = p0; GL[0][h2][h] = p0;
            GL[1][h][h2] = p1; GL[1][h2][h] = p1;
        }
    }
    __syncthreads();   // (#2) GL, hs, Hsum partials

    // ---- centered-z1 bf16 fragments, both rows (t = d) ----
    #pragma unroll
    for (int r = 0; r < 2; r++) {
        unsigned short pk[8];
        #pragma unroll
        for (int h = 0; h < NH; h++) {
            float c = z1s[r][h * S1 + t] - GL[r][h][8] * (1.0f / 256.0f);
            pk[h] = f2bf(c);
        }
        ushort4 lo = {pk[0], pk[1], pk[2], pk[3]};
        ushort4 hi = {pk[4], pk[5], pk[6], pk[7]};
        *(ushort4*)(&z1cb[r][t * 8])     = lo;
        *(ushort4*)(&z1cb[r][t * 8 + 4]) = hi;
    }
    // ---- stats + scaled-z2 bf16 fragments, both rows (t < 128, g = t) ----
    if (t < DG) {
        #pragma unroll
        for (int r = 0; r < 2; r++) {
            float z2g[NH];
            #pragma unroll
            for (int h = 0; h < NH; h++) z2g[h] = z2s[r][h * DG + t];
            float mug = 0.f, qg = 0.f;
            #pragma unroll
            for (int h = 0; h < NH; h++) {
                mug += z2g[h] * GL[r][h][8];
                float inn = 0.f;
                #pragma unroll
                for (int h2 = 0; h2 < NH; h2++) inn += z2g[h2] * GL[r][h][h2];
                qg += z2g[h] * inn;
            }
            mug *= (1.0f / 256.0f);
            qg  *= (1.0f / 256.0f);
            float vg = fmaxf(qg - mug * mug, 0.0f);
            float A = 2.0f * 1.4426950408889634f / (sqrtf(vg) + 1e-6f);
            unsigned short pk[8];
            #pragma unroll
            for (int h = 0; h < NH; h++) pk[h] = f2bf(z2g[h] * A);
            ushort4 lo = {pk[0], pk[1], pk[2], pk[3]};
            ushort4 hi = {pk[4], pk[5], pk[6], pk[7]};
            *(ushort4*)(&z2A[r][t * 8])     = lo;
            *(ushort4*)(&z2A[r][t * 8 + 4]) = hi;
        }
    }
    __syncthreads();   // (#3) fragments ready

    // ---- main: per wave 2 g-tiles x 16 d-tiles x 2 rows ----
    const int lrow = lane & 15, q = lane >> 4;
    const unsigned short* bp0 = (q == 0) ? (&z1cb[0][lrow * 8]) : zpad;
    const unsigned short* bp1 = (q == 0) ? (&z1cb[1][lrow * 8]) : zpad;
    const int binc = (q == 0) ? 128 : 0;
    bf16x8 af[2][2];
    #pragma unroll
    for (int r = 0; r < 2; r++)
        #pragma unroll
        for (int gt = 0; gt < 2; gt++) {
            const unsigned short* aptr =
                (q == 0) ? (&z2A[r][(wv * 32 + gt * 16 + lrow) * 8]) : zpad;
            af[r][gt] = *reinterpret_cast<const bf16x8*>(aptr);
        }
    f32x4 czero = {};
    float yn[2][2][4] = {};
    #pragma unroll 2
    for (int dt = 0; dt < 16; dt++) {
        bf16x8 bf0 = *reinterpret_cast<const bf16x8*>(bp0 + dt * binc);
        bf16x8 bf1 = *reinterpret_cast<const bf16x8*>(bp1 + dt * binc);
        float hv0 = hs[0][dt * 16 + lrow];
        float hv1 = hs[1][dt * 16 + lrow];
        #pragma unroll
        for (int gt = 0; gt < 2; gt++) {
            f32x4 c0 = __builtin_amdgcn_mfma_f32_16x16x32_bf16(af[0][gt], bf0, czero, 0, 0, 0);
            f32x4 c1 = __builtin_amdgcn_mfma_f32_16x16x32_bf16(af[1][gt], bf1, czero, 0, 0, 0);
            #pragma unroll
            for (int r4 = 0; r4 < 4; r4++) {
                float e0 = __builtin_amdgcn_exp2f(c0[r4]);
                yn[0][gt][r4] = fmaf(hv0, __builtin_amdgcn_rcpf(e0 + 1.0f), yn[0][gt][r4]);
                float e1 = __builtin_amdgcn_exp2f(c1[r4]);
                yn[1][gt][r4] = fmaf(hv1, __builtin_amdgcn_rcpf(e1 + 1.0f), yn[1][gt][r4]);
            }
        }
    }
    #pragma unroll
    for (int m = 1; m <= 8; m <<= 1)
        #pragma unroll
        for (int r = 0; r < 2; r++)
            #pragma unroll
            for (int gt = 0; gt < 2; gt++)
                #pragma unroll
                for (int r4 = 0; r4 < 4; r4++)
                    yn[r][gt][r4] += __shfl_xor(yn[r][gt][r4], m, 64);
    if (lrow == 0) {
        #pragma unroll
        for (int r = 0; r < 2; r++) {
            float Hsum = red[r][0][2] + red[r][1][2] + red[r][2][2] + red[r][3][2];
            #pragma unroll
            for (int gt = 0; gt < 2; gt++)
                #pragma unroll
                for (int r4 = 0; r4 < 4; r4++)
                    y_out[(size_t)(b0 + r) * DG + wv * 32 + gt * 16 + q * 4 + r4] =
                        Hsum - 2.0f * yn[r][gt][r4];
        }
    }
}

extern "C" void kernel_launch(void* const* d_in, const int* in_sizes, int n_in,
                              void* d_out, int out_size, void* d_ws, size_t ws_size,
                              hipStream_t stream) {
    const float* x   = (const float*)d_in[0];
    const float* Wh  = (const float*)d_in[1];
    const float* bh  = (const float*)d_in[2];
    const float* Wz1 = (const float*)d_in[3];
    const float* Wz2 = (const float*)d_in[4];
    const float* lns = (const float*)d_in[5];
    const float* lnb = (const float*)d_in[6];
    float* h_out = (float*)d_out;
    float* y_out = h_out + (size_t)BATCH * DH;

    char* ws = (char*)d_ws;
    unsigned short* Zb = (unsigned short*)ws;               // 27,262,976 B
    unsigned short* xb = (unsigned short*)(ws + 27262976);  //  4,194,304 B
    unsigned short* Wt = (unsigned short*)(ws + 31457280);  //  3,407,872 B (~34.9 MB)

    prep_kernel<<<3712, 256, 0, stream>>>(x, Wh, Wz1, Wz2, xb, Wt);
    gemm_kernel<<<dim3(NTOT / 128, BATCH / 128), 256, 0, stream>>>(xb, Wt, Zb);
    attn_kernel<<<BATCH / 2, 256, 0, stream>>>(Zb, bh, lns, lnb, h_out, y_out);
}

// Round 7
// 144.079 us; speedup vs baseline: 1.1404x; 1.1404x over previous
//
#include <hip/hip_runtime.h>
#include <hip/hip_bf16.h>
#include <cstdint>

#define BATCH 4096
#define DIN   512
#define DH    256
#define DG    128
#define NH    8
#define NTOT  3328
#define S2    264    // padded bf16 (shorts) row stride for z1 LDS: 528B rows -> 2-way banks (free)

typedef __bf16 bf16x8 __attribute__((ext_vector_type(8)));
typedef float  f32x4  __attribute__((ext_vector_type(4)));

__device__ __forceinline__ unsigned short f2bf(float f) {
    union { float f; uint32_t u; } v; v.f = f;
    uint32_t u = v.u;
    u += 0x7fffu + ((u >> 16) & 1u);
    return (unsigned short)(u >> 16);
}
__device__ __forceinline__ float bf2f(unsigned short s) {
    union { uint32_t u; float f; } v; v.u = ((uint32_t)s) << 16;
    return v.f;
}

__device__ __forceinline__ void async16(const unsigned short* g, unsigned short* l) {
    __builtin_amdgcn_global_load_lds(
        (const __attribute__((address_space(1))) unsigned int*)(uintptr_t)g,
        (__attribute__((address_space(3))) unsigned int*)(uintptr_t)l,
        16, 0, 0);
}

// ---------------- merged prep: cvt_x + transpose/concat weights (R5-proven) ----------------
__global__ __launch_bounds__(256) void prep_kernel(const float* __restrict__ x,
                                                   const float* __restrict__ Wh,
                                                   const float* __restrict__ Wz1,
                                                   const float* __restrict__ Wz2,
                                                   unsigned short* __restrict__ xb,
                                                   unsigned short* __restrict__ Wt) {
    __shared__ float tile[32][33];
    int bid = blockIdx.x;
    int t = threadIdx.x;
    if (bid < 2048) {
        int i = (bid * 256 + t) * 4;
        float4 v = *(const float4*)(x + i);
        ushort4 o;
        o.x = f2bf(v.x); o.y = f2bf(v.y); o.z = f2bf(v.z); o.w = f2bf(v.w);
        *(ushort4*)(xb + i) = o;
        return;
    }
    int b2 = bid - 2048;
    int n0 = (b2 % 104) * 32;
    int k0 = (b2 / 104) * 32;
    const float* W; int ldn, nl;
    if (n0 < 256)       { W = Wh;  ldn = 256;  nl = n0; }
    else if (n0 < 2304) { W = Wz1; ldn = 2048; nl = n0 - 256; }
    else                { W = Wz2; ldn = 1024; nl = n0 - 2304; }
    int tx = t & 31, ty = t >> 5;
    #pragma unroll
    for (int i = 0; i < 4; i++) {
        int kk = ty + i * 8;
        tile[kk][tx] = W[(size_t)(k0 + kk) * ldn + nl + tx];
    }
    __syncthreads();
    #pragma unroll
    for (int i = 0; i < 4; i++) {
        int nn = ty + i * 8;
        Wt[(size_t)(n0 + nn) * 512 + k0 + tx] = f2bf(tile[tx][nn]);
    }
}

// ------------- fused GEMM: Zb[4096][3328](bf16) = xb @ Wt^T (R5-proven) -------------
__global__ __launch_bounds__(256) void gemm_kernel(const unsigned short* __restrict__ xb,
                                                   const unsigned short* __restrict__ Wt,
                                                   unsigned short* __restrict__ Zb) {
    __shared__ unsigned short As[128 * 64];
    __shared__ unsigned short Bs[128 * 64];
    const int m0 = blockIdx.y * 128;
    const int n0 = blockIdx.x * 128;
    const int t = threadIdx.x;
    const int w = t >> 6, lane = t & 63;
    const int wm = (w >> 1) * 64, wn = (w & 1) * 64;
    const int lrow = lane & 15, q = lane >> 4;

    f32x4 acc[4][4] = {};

    for (int k0 = 0; k0 < DIN; k0 += 64) {
        __syncthreads();
        #pragma unroll
        for (int j = 0; j < 4; j++) {
            int gidx = (w * 4 + j) * 64 + lane;
            int row = gidx >> 3, slot = gidx & 7;
            int src = slot ^ (row & 7);
            const unsigned short* ga = xb + (size_t)(m0 + row) * DIN + k0 + src * 8;
            const unsigned short* gb = Wt + (size_t)(n0 + row) * DIN + k0 + src * 8;
            async16(ga, As + (w * 4 + j) * 512);
            async16(gb, Bs + (w * 4 + j) * 512);
        }
        __syncthreads();
        #pragma unroll
        for (int ks = 0; ks < 2; ks++) {
            bf16x8 af[4], bfr[4];
            #pragma unroll
            for (int i = 0; i < 4; i++) {
                int row = wm + i * 16 + lrow;
                int phys = (ks * 4 + q) ^ (row & 7);
                af[i] = *reinterpret_cast<const bf16x8*>(As + row * 64 + phys * 8);
            }
            #pragma unroll
            for (int j = 0; j < 4; j++) {
                int row = wn + j * 16 + lrow;
                int phys = (ks * 4 + q) ^ (row & 7);
                bfr[j] = *reinterpret_cast<const bf16x8*>(Bs + row * 64 + phys * 8);
            }
            #pragma unroll
            for (int i = 0; i < 4; i++)
                #pragma unroll
                for (int j = 0; j < 4; j++)
                    acc[i][j] = __builtin_amdgcn_mfma_f32_16x16x32_bf16(af[i], bfr[j], acc[i][j], 0, 0, 0);
        }
    }
    #pragma unroll
    for (int i = 0; i < 4; i++)
        #pragma unroll
        for (int j = 0; j < 4; j++) {
            int col = n0 + wn + j * 16 + lrow;
            int rbase = m0 + wm + i * 16 + q * 4;
            #pragma unroll
            for (int r = 0; r < 4; r++)
                Zb[(size_t)(rbase + r) * NTOT + col] = f2bf(acc[i][j][r]);
        }
}

// ------- per-batch: LN -> h ; MFMA Gram ; MFMA standardize+tanh ; y -------
// z1/z2 stay bf16 in LDS (raw copies). Gram G = z1aug z1aug^T via 8 MFMAs on
// wave 3 (A=B fragment; garbage rows 9..15 only pollute unused C entries).
__global__ __launch_bounds__(256) void attn_kernel(const unsigned short* __restrict__ Zb,
                                                   const float* __restrict__ bh,
                                                   const float* __restrict__ lns,
                                                   const float* __restrict__ lnb,
                                                   float* __restrict__ h_out,
                                                   float* __restrict__ y_out) {
    __shared__ unsigned short z1s[16 * S2];    // bf16 [h][d]; rows 0..7 z1, row 8 ones, 9..15 uninit
    __shared__ unsigned short z2s[NH * DG];    // bf16 [h*128+g]
    __shared__ unsigned short z1cb[DH * 8];    // centered z1 bf16 [d][h]
    __shared__ unsigned short z2A[DG * 8];     // z2*A bf16 [g][h]
    __shared__ unsigned short zpad[8];         // 16B zeros
    __shared__ float hs[DH];
    __shared__ float GL[9][9];
    __shared__ float red[4][3];
    const int b = blockIdx.x;
    const int t = threadIdx.x;
    const int wv = t >> 6, lane = t & 63;
    const int lrow = lane & 15, q = lane >> 4;
    const unsigned short* Zrow = Zb + (size_t)b * NTOT;

    // ---- stage: raw bf16 copies, no conversion ----
    {
        uint4 v1 = *(const uint4*)(Zrow + 256 + t * 8);
        *(uint4*)(z1s + (t >> 5) * S2 + (t & 31) * 8) = v1;
        if (t < 128) {
            uint4 v2 = *(const uint4*)(Zrow + 2304 + t * 8);
            *(uint4*)(z2s + t * 8) = v2;
        }
        z1s[8 * S2 + t] = 0x3F80;   // bf16 1.0 (ones row)
        if (t < 8) zpad[t] = 0;
    }
    // ---- LN partials (hpre direct from global) ----
    float v = fmaxf(bf2f(Zrow[t]) + bh[t], 0.0f);
    float s = v, sq = v * v;
    #pragma unroll
    for (int m = 32; m >= 1; m >>= 1) {
        s  += __shfl_xor(s,  m, 64);
        sq += __shfl_xor(sq, m, 64);
    }
    if (lane == 0) { red[wv][0] = s; red[wv][1] = sq; }
    __syncthreads();   // (#1) staging + LN partials

    // ---- Gram via MFMA (wave 3 only; wave-uniform branch) ----
    if (wv == 3) {
        f32x4 g = {};
        #pragma unroll
        for (int ks = 0; ks < 8; ks++) {
            bf16x8 fr = *reinterpret_cast<const bf16x8*>(z1s + lrow * S2 + ks * 32 + q * 8);
            g = __builtin_amdgcn_mfma_f32_16x16x32_bf16(fr, fr, g, 0, 0, 0);
        }
        // C[row = q*4+r][col = lrow]; keep rows/cols 0..8
        #pragma unroll
        for (int r = 0; r < 4; r++) {
            int row = q * 4 + r;
            if (row < 9 && lrow < 9) GL[row][lrow] = g[r];
        }
    }
    // ---- LN final -> h, Hsum partials ----
    {
        float ss = red[0][0] + red[1][0] + red[2][0] + red[3][0];
        float qq = red[0][1] + red[1][1] + red[2][1] + red[3][1];
        float mu  = ss * (1.0f / 256.0f);
        float var = qq * (1.0f / 256.0f) - mu * mu;
        float hval = (v - mu) * rsqrtf(var + 1e-6f) * lns[t] + lnb[t];
        hs[t] = hval;
        h_out[(size_t)b * DH + t] = hval;
        float hp = hval;
        #pragma unroll
        for (int m = 32; m >= 1; m >>= 1) hp += __shfl_xor(hp, m, 64);
        if (lane == 0) red[wv][2] = hp;
    }
    __syncthreads();   // (#2) GL + hs + Hsum partials

    // ---- repack centered z1 -> [d][h] bf16 (all threads, t = d) ----
    {
        unsigned short pk[8];
        #pragma unroll
        for (int h = 0; h < NH; h++) {
            float c = bf2f(z1s[h * S2 + t]) - GL[h][8] * (1.0f / 256.0f);
            pk[h] = f2bf(c);
        }
        ushort4 lo = {pk[0], pk[1], pk[2], pk[3]};
        ushort4 hi = {pk[4], pk[5], pk[6], pk[7]};
        *(ushort4*)(z1cb + t * 8)     = lo;
        *(ushort4*)(z1cb + t * 8 + 4) = hi;
    }
    // ---- stats + scaled-z2 bf16 fragments (t < 128, g = t) ----
    if (t < DG) {
        float z2g[NH];
        #pragma unroll
        for (int h = 0; h < NH; h++) z2g[h] = bf2f(z2s[h * DG + t]);
        float mug = 0.f, qg = 0.f;
        #pragma unroll
        for (int h = 0; h < NH; h++) {
            mug += z2g[h] * GL[h][8];
            float inn = 0.f;
            #pragma unroll
            for (int h2 = 0; h2 < NH; h2++) inn += z2g[h2] * GL[h][h2];
            qg += z2g[h] * inn;
        }
        mug *= (1.0f / 256.0f);
        qg  *= (1.0f / 256.0f);
        float vg = fmaxf(qg - mug * mug, 0.0f);
        float A = 2.0f * 1.4426950408889634f / (sqrtf(vg) + 1e-6f);
        unsigned short pk[8];
        #pragma unroll
        for (int h = 0; h < NH; h++) pk[h] = f2bf(z2g[h] * A);
        ushort4 lo = {pk[0], pk[1], pk[2], pk[3]};
        ushort4 hi = {pk[4], pk[5], pk[6], pk[7]};
        *(ushort4*)(z2A + t * 8)     = lo;
        *(ushort4*)(z2A + t * 8 + 4) = hi;
    }
    __syncthreads();   // (#3) fragments ready

    // ---- main: per wave 2 g-tiles of 16, 16 d-tiles; hv preloaded ----
    const unsigned short* bptr = (q == 0) ? (z1cb + lrow * 8) : zpad;
    const int binc = (q == 0) ? 128 : 0;
    bf16x8 af[2];
    #pragma unroll
    for (int gt = 0; gt < 2; gt++) {
        const unsigned short* aptr = (q == 0) ? (z2A + (wv * 32 + gt * 16 + lrow) * 8) : zpad;
        af[gt] = *reinterpret_cast<const bf16x8*>(aptr);
    }
    float hv[16];
    #pragma unroll
    for (int dt = 0; dt < 16; dt++) hv[dt] = hs[dt * 16 + lrow];

    f32x4 czero = {};
    float yn[2][4] = {};
    #pragma unroll 4
    for (int dt = 0; dt < 16; dt++) {
        bf16x8 bfr = *reinterpret_cast<const bf16x8*>(bptr + dt * binc);
        #pragma unroll
        for (int gt = 0; gt < 2; gt++) {
            f32x4 c = __builtin_amdgcn_mfma_f32_16x16x32_bf16(af[gt], bfr, czero, 0, 0, 0);
            #pragma unroll
            for (int r = 0; r < 4; r++) {
                float e = __builtin_amdgcn_exp2f(c[r]);
                yn[gt][r] = fmaf(hv[dt], __builtin_amdgcn_rcpf(e + 1.0f), yn[gt][r]);
            }
        }
    }
    #pragma unroll
    for (int m = 1; m <= 8; m <<= 1)
        #pragma unroll
        for (int gt = 0; gt < 2; gt++)
            #pragma unroll
            for (int r = 0; r < 4; r++)
                yn[gt][r] += __shfl_xor(yn[gt][r], m, 64);
    if (lrow == 0) {
        float Hsum = red[0][2] + red[1][2] + red[2][2] + red[3][2];
        #pragma unroll
        for (int gt = 0; gt < 2; gt++)
            #pragma unroll
            for (int r = 0; r < 4; r++)
                y_out[(size_t)b * DG + wv * 32 + gt * 16 + q * 4 + r] = Hsum - 2.0f * yn[gt][r];
    }
}

extern "C" void kernel_launch(void* const* d_in, const int* in_sizes, int n_in,
                              void* d_out, int out_size, void* d_ws, size_t ws_size,
                              hipStream_t stream) {
    const float* x   = (const float*)d_in[0];
    const float* Wh  = (const float*)d_in[1];
    const float* bh  = (const float*)d_in[2];
    const float* Wz1 = (const float*)d_in[3];
    const float* Wz2 = (const float*)d_in[4];
    const float* lns = (const float*)d_in[5];
    const float* lnb = (const float*)d_in[6];
    float* h_out = (float*)d_out;
    float* y_out = h_out + (size_t)BATCH * DH;

    char* ws = (char*)d_ws;
    unsigned short* Zb = (unsigned short*)ws;               // 27,262,976 B
    unsigned short* xb = (unsigned short*)(ws + 27262976);  //  4,194,304 B
    unsigned short* Wt = (unsigned short*)(ws + 31457280);  //  3,407,872 B (~34.9 MB)

    prep_kernel<<<3712, 256, 0, stream>>>(x, Wh, Wz1, Wz2, xb, Wt);
    gemm_kernel<<<dim3(NTOT / 128, BATCH / 128), 256, 0, stream>>>(xb, Wt, Zb);
    attn_kernel<<<BATCH, 256, 0, stream>>>(Zb, bh, lns, lnb, h_out, y_out);
}